// Round 1
// 682.485 us; speedup vs baseline: 1.0383x; 1.0383x over previous
//
#include <hip/hip_runtime.h>
#include <cstdint>
#include <cstddef>

typedef __attribute__((ext_vector_type(4))) float    f32x4;
typedef __attribute__((ext_vector_type(8))) __bf16   bf16x8;
typedef __attribute__((ext_vector_type(4))) short    s16x4;
typedef __attribute__((ext_vector_type(4))) uint32_t u32x4;
typedef __attribute__((ext_vector_type(2))) uint32_t u32x2;

__device__ __forceinline__ float bf2f(uint16_t h) {
    uint32_t u = ((uint32_t)h) << 16;
    return __builtin_bit_cast(float, u);
}
__device__ __forceinline__ uint16_t f2bf(float f) {
    uint32_t u = __builtin_bit_cast(uint32_t, f);
    uint32_t r = (u + 0x7fffu + ((u >> 16) & 1u)) >> 16;  // RNE
    return (uint16_t)r;
}
// native HW convert (RNE) — for hot loops
__device__ __forceinline__ uint16_t f2bf_fast(float f) {
    __bf16 h = (__bf16)f;
    return __builtin_bit_cast(uint16_t, h);
}

__device__ __forceinline__ f32x4 mfma32(bf16x8 a, bf16x8 b, f32x4 c) {
    return __builtin_amdgcn_mfma_f32_16x16x32_bf16(a, b, c, 0, 0, 0);
}
__device__ __forceinline__ f32x4 mfma16(s16x4 a, s16x4 b, f32x4 c) {
    return __builtin_amdgcn_mfma_f32_16x16x16bf16_1k(a, b, c, 0, 0, 0);
}

// async global->LDS, 16B per lane (GEMM staging)
__device__ __forceinline__ void gload16(const void* g, void* l) {
    __builtin_amdgcn_global_load_lds(
        (const __attribute__((address_space(1))) uint32_t*)g,
        (__attribute__((address_space(3))) uint32_t*)l, 16, 0, 0);
}

// ---------------------------------------------------------------------------
// fp32 -> bf16 elementwise, 4 elems/thread/iter, grid-stride
// ---------------------------------------------------------------------------
__global__ __launch_bounds__(256) void cvt_bf16(
    const float* __restrict__ s, uint16_t* __restrict__ d, int n4)
{
    int i = blockIdx.x * 256 + threadIdx.x;
    const int stride = gridDim.x * 256;
    for (; i < n4; i += stride) {
        f32x4 v = ((const f32x4*)s)[i];
        u32x2 p;
        p[0] = (uint32_t)f2bf(v[0]) | ((uint32_t)f2bf(v[1]) << 16);
        p[1] = (uint32_t)f2bf(v[2]) | ((uint32_t)f2bf(v[3]) << 16);
        ((u32x2*)d)[i] = p;
    }
}

// ---------------------------------------------------------------------------
// C[M,N] = A[M,K] @ B[N,K]^T, bf16 in, fp32 acc.  (m97 structure)
// ---------------------------------------------------------------------------
template <bool F32OUT>
__global__ __launch_bounds__(256) void gemm_bt(
    const uint16_t* __restrict__ A, const uint16_t* __restrict__ B,
    void* __restrict__ Cv, const float* __restrict__ R,
    int M, int N, int K)
{
    __shared__ __align__(16) uint16_t lA[128 * 32];
    __shared__ __align__(16) uint16_t lB[128 * 32];
    const int tid = threadIdx.x;
    const int wv = tid >> 6, ln = tid & 63;
    const int l15 = ln & 15, q = ln >> 4;
    const int m0 = blockIdx.y * 128, n0 = blockIdx.x * 128;
    const int wm = (wv >> 1) * 64, wn = (wv & 1) * 64;

    const uint16_t* ga = A + (size_t)(m0 + wv * 32 + (ln >> 2)) * K + (ln & 3) * 8;
    const uint16_t* gb = B + (size_t)(n0 + wv * 32 + (ln >> 2)) * K + (ln & 3) * 8;
    uint16_t* la = lA + (wv * 32) * 32;
    uint16_t* lb = lB + (wv * 32) * 32;

    f32x4 acc[4][4];
    for (int i = 0; i < 4; i++)
        for (int j = 0; j < 4; j++)
            acc[i][j] = (f32x4){0.f, 0.f, 0.f, 0.f};

    for (int kt = 0; kt < K; kt += 32) {
        gload16(ga + kt, la);
        gload16(ga + (size_t)16 * K + kt, la + 16 * 32);
        gload16(gb + kt, lb);
        gload16(gb + (size_t)16 * K + kt, lb + 16 * 32);
        __syncthreads();

        bf16x8 af[4], bfv[4];
        for (int mt = 0; mt < 4; mt++)
            af[mt] = __builtin_bit_cast(bf16x8,
                *(const u32x4*)(lA + (wm + mt * 16 + l15) * 32 + q * 8));
        for (int nt = 0; nt < 4; nt++)
            bfv[nt] = __builtin_bit_cast(bf16x8,
                *(const u32x4*)(lB + (wn + nt * 16 + l15) * 32 + q * 8));
        for (int mt = 0; mt < 4; mt++)
            for (int nt = 0; nt < 4; nt++)
                acc[mt][nt] = mfma32(af[mt], bfv[nt], acc[mt][nt]);
        __syncthreads();
    }

    for (int mt = 0; mt < 4; mt++)
        for (int nt = 0; nt < 4; nt++)
            for (int r = 0; r < 4; r++) {
                int row = m0 + wm + mt * 16 + q * 4 + r;
                int col = n0 + wn + nt * 16 + l15;
                size_t idx = (size_t)row * N + col;
                float v = acc[mt][nt][r];
                if (F32OUT) {
                    ((float*)Cv)[idx] = v + R[idx];
                } else {
                    ((uint16_t*)Cv)[idx] = f2bf(v);
                }
            }
}

// ---------------------------------------------------------------------------
// repack + fused RoPE: per (b,h,c) emit contiguous tiles
//   kp[g][m16][d128], kt[g][d128][m16], vt[g][e128][m16];  g=((b*16)+h)*128+c
// ---------------------------------------------------------------------------
__global__ __launch_bounds__(64) void repack(
    const uint16_t* __restrict__ kb, const uint16_t* __restrict__ vb,
    uint16_t* __restrict__ kp, uint16_t* __restrict__ kt,
    uint16_t* __restrict__ vt)
{
    const int g = blockIdx.x;
    const int c = g & 127, h = (g >> 7) & 15, b = g >> 11;
    const int ln = threadIdx.x;
    const int m = ln >> 2, cb = (ln & 3) * 32;
    const size_t tok = (size_t)b * 2048 + c * 16 + m;
    const int s = c * 16 + m;
    const uint16_t* krow = kb + tok * 2048 + h * 128;
    const uint16_t* vrow = vb + tok * 2048 + h * 128;

    u32x4 kraw[4], praw[4], vraw[4];
    for (int i = 0; i < 4; i++) {
        kraw[i] = *(const u32x4*)(krow + cb + 8 * i);
        praw[i] = *(const u32x4*)(krow + (cb ^ 64) + 8 * i);
        vraw[i] = *(const u32x4*)(vrow + cb + 8 * i);
    }
    const uint16_t* ku = (const uint16_t*)kraw;
    const uint16_t* pu = (const uint16_t*)praw;
    const uint16_t* vu = (const uint16_t*)vraw;

    uint16_t ko[32];
    for (int j = 0; j < 32; j++) {
        int col = cb + j;
        int p = col & 63;
        float invf = exp2f((float)p * (-13.287712379549449f / 64.0f));
        float a = (float)s * invf;
        float sn, cs;
        __sincosf(a, &sn, &cs);
        float u1 = bf2f(ku[j]), u2 = bf2f(pu[j]);
        float o = (col < 64) ? (u1 * cs - u2 * sn) : (u1 * cs + u2 * sn);
        ko[j] = f2bf(o);
    }

    uint16_t* kpg = kp + (size_t)g * 2048;
    uint16_t* ktg = kt + (size_t)g * 2048;
    uint16_t* vtg = vt + (size_t)g * 2048;
    for (int i = 0; i < 4; i++) {
        u32x4 pk;
        uint32_t* pw = (uint32_t*)&pk;
        for (int w = 0; w < 4; w++)
            pw[w] = (uint32_t)ko[8 * i + 2 * w] | ((uint32_t)ko[8 * i + 2 * w + 1] << 16);
        *(u32x4*)(kpg + m * 128 + cb + 8 * i) = pk;
    }
    for (int j = 0; j < 32; j++) {
        ktg[(cb + j) * 16 + m] = ko[j];
        vtg[(cb + j) * 16 + m] = vu[j];
    }
}

// ---------------------------------------------------------------------------
// TTT scan v2: one single-wave block per (b,h,e-slice) -> 256 blocks, one per
// CU. Slice s of group g is block (s*64 + g), so the 4 siblings that share
// kp/kt tiles have equal bid%8 -> same XCD -> shared L2.
// No LDS staging, no s_barrier: k/kt/vt MFMA fragments are loaded directly
// from global (L2-resident, 2-deep register double-buffer). LDS holds only
// this wave's bf16 W-shadow [e32][d128+8] (pred B-operand); W master fp32 in
// registers. pred = k@W; G = k k^T; errS = (v-pred)/1024; W += k^T@errS;
// out = pred + G@errS.
// ---------------------------------------------------------------------------
__global__ __launch_bounds__(64, 1) void ttt_scan(
    const uint16_t* __restrict__ kp, const uint16_t* __restrict__ kt,
    const uint16_t* __restrict__ vt, const float* __restrict__ W0,
    uint16_t* __restrict__ O)
{
    __shared__ __align__(16) uint16_t wbp[32 * 136];   // [e][d] +8 pad

    const int bid = blockIdx.x;
    const int g  = bid & 63;            // (b,h) group
    const int e0 = (bid >> 6) * 32;     // e-slice; siblings bid+{64,128,192}
    const int h = g & 15, b = g >> 4;
    const int ln = threadIdx.x;
    const int l15 = ln & 15, q = ln >> 4;

    // W[mt][nt] reg r holds W[d = 16mt+4q+r][e = e0+16nt+l15]  (fp32 master)
    f32x4 W[8][2];
    {
        const float* w0p = W0 + (size_t)g * 128 * 128;
        for (int mt = 0; mt < 8; mt++)
            for (int nt = 0; nt < 2; nt++)
                for (int r = 0; r < 4; r++)
                    W[mt][nt][r] = w0p[(size_t)(16 * mt + 4 * q + r) * 128
                                       + e0 + 16 * nt + l15];
    }
    #pragma unroll
    for (int mt = 0; mt < 8; mt++)
        for (int nt = 0; nt < 2; nt++) {
            uint32_t p0 = (uint32_t)f2bf_fast(W[mt][nt][0]) | ((uint32_t)f2bf_fast(W[mt][nt][1]) << 16);
            uint32_t p1 = (uint32_t)f2bf_fast(W[mt][nt][2]) | ((uint32_t)f2bf_fast(W[mt][nt][3]) << 16);
            int e = 16 * nt + l15, d = 16 * mt + 4 * q;
            u32x2 pp; pp[0] = p0; pp[1] = p1;
            *(u32x2*)(wbp + e * 136 + d) = pp;
        }
    asm volatile("s_waitcnt lgkmcnt(0)" ::: "memory");
    __builtin_amdgcn_wave_barrier();

    const uint16_t* kpw = kp + (size_t)g * 128 * 2048;
    const uint16_t* ktw = kt + (size_t)g * 128 * 2048;
    const uint16_t* vtw = vt + (size_t)g * 128 * 2048;
    uint16_t*     obase = O  + (size_t)b * 2048 * 2048 + h * 128 + e0;

    // fragment prefetch (direct from global; tiles are L2-hot on this XCD)
    auto loadset = [&](int c, u32x4* afr, u32x2* ktr, u32x2* vvr) {
        const uint16_t* kc = kpw + (size_t)c * 2048;
        const uint16_t* tc = ktw + (size_t)c * 2048;
        const uint16_t* vc = vtw + (size_t)c * 2048;
        #pragma unroll
        for (int ks = 0; ks < 4; ks++)
            afr[ks] = *(const u32x4*)(kc + l15 * 128 + ks * 32 + q * 8);
        #pragma unroll
        for (int mt = 0; mt < 8; mt++)
            ktr[mt] = *(const u32x2*)(tc + (16 * mt + l15) * 16 + 4 * q);
        vvr[0] = *(const u32x2*)(vc + (e0 + l15) * 16 + 4 * q);
        vvr[1] = *(const u32x2*)(vc + (e0 + 16 + l15) * 16 + 4 * q);
    };

    auto step = [&](int c, const u32x4* afr, const u32x2* ktr, const u32x2* vvr) {
        const int s0 = c * 16;

        // pred (2 n-tiles) and G = k k^T; B-operands from the W-shadow
        f32x4 acc0 = (f32x4){0.f, 0.f, 0.f, 0.f};
        f32x4 acc1 = (f32x4){0.f, 0.f, 0.f, 0.f};
        f32x4 gacc = (f32x4){0.f, 0.f, 0.f, 0.f};
        #pragma unroll
        for (int ks = 0; ks < 4; ks++) {
            bf16x8 a  = __builtin_bit_cast(bf16x8, afr[ks]);
            bf16x8 b0 = __builtin_bit_cast(bf16x8,
                *(const u32x4*)(wbp + l15 * 136 + ks * 32 + q * 8));
            bf16x8 b1 = __builtin_bit_cast(bf16x8,
                *(const u32x4*)(wbp + (16 + l15) * 136 + ks * 32 + q * 8));
            acc0 = mfma32(a, b0, acc0);
            acc1 = mfma32(a, b1, acc1);
            gacc = mfma32(a, a, gacc);
        }

        // errS = (v - pred)/1024, already in 16x16x16 A/B operand layout
        s16x4 vv0 = __builtin_bit_cast(s16x4, vvr[0]);
        s16x4 vv1 = __builtin_bit_cast(s16x4, vvr[1]);
        s16x4 es0, es1, gf;
        #pragma unroll
        for (int r = 0; r < 4; r++) {
            es0[r] = (short)f2bf_fast((bf2f((uint16_t)vv0[r]) - acc0[r]) * (1.0f / 1024.0f));
            es1[r] = (short)f2bf_fast((bf2f((uint16_t)vv1[r]) - acc1[r]) * (1.0f / 1024.0f));
            gf[r]  = (short)f2bf_fast(gacc[r]);
        }

        // out = pred + G @ errS
        f32x4 o0 = mfma16(gf, es0, acc0);
        f32x4 o1 = mfma16(gf, es1, acc1);

        // W update: W += k^T @ errS
        #pragma unroll
        for (int mt = 0; mt < 8; mt++) {
            s16x4 kf = __builtin_bit_cast(s16x4, ktr[mt]);
            W[mt][0] = mfma16(kf, es0, W[mt][0]);
            W[mt][1] = mfma16(kf, es1, W[mt][1]);
        }

        // store out chunk (fire-and-forget)
        #pragma unroll
        for (int r = 0; r < 4; r++) {
            obase[(size_t)(s0 + 4 * q + r) * 2048 + l15]      = f2bf_fast(o0[r]);
            obase[(size_t)(s0 + 4 * q + r) * 2048 + 16 + l15] = f2bf_fast(o1[r]);
        }

        __builtin_amdgcn_wave_barrier();   // shadow reads done before rewrite
        #pragma unroll
        for (int mt = 0; mt < 8; mt++)
            for (int nt = 0; nt < 2; nt++) {
                uint32_t p0 = (uint32_t)f2bf_fast(W[mt][nt][0]) | ((uint32_t)f2bf_fast(W[mt][nt][1]) << 16);
                uint32_t p1 = (uint32_t)f2bf_fast(W[mt][nt][2]) | ((uint32_t)f2bf_fast(W[mt][nt][3]) << 16);
                int e = 16 * nt + l15, d = 16 * mt + 4 * q;
                u32x2 pp; pp[0] = p0; pp[1] = p1;
                *(u32x2*)(wbp + e * 136 + d) = pp;
            }
        asm volatile("s_waitcnt lgkmcnt(0)" ::: "memory");   // writes land
        __builtin_amdgcn_wave_barrier();   // rewrite before next step's reads
    };

    u32x4 afA[4], afB[4];
    u32x2 ktA[8], ktB[8];
    u32x2 vvA[2], vvB[2];
    loadset(0, afA, ktA, vvA);
    loadset(1, afB, ktB, vvB);

    for (int c = 0; c < 128; c += 2) {
        step(c, afA, ktA, vvA);
        if (c < 126) loadset(c + 2, afA, ktA, vvA);
        step(c + 1, afB, ktB, vvB);
        if (c < 126) loadset(c + 3, afB, ktB, vvB);
    }
}

// ---------------------------------------------------------------------------
// LayerNorm over rows of 2048 (biased var), * g + b; X bf16, g/b fp32, Y bf16
// ---------------------------------------------------------------------------
__global__ __launch_bounds__(256) void ln_kernel(
    const uint16_t* __restrict__ X, const float* __restrict__ Gm,
    const float* __restrict__ Bt, uint16_t* __restrict__ Y)
{
    const int row = blockIdx.x, t = threadIdx.x;
    const uint16_t* xr = X + (size_t)row * 2048 + t * 8;
    u32x4 raw = *(const u32x4*)xr;
    const uint16_t* pr = (const uint16_t*)&raw;
    float v[8];
    float s = 0.f, s2 = 0.f;
    for (int i = 0; i < 8; i++) {
        v[i] = bf2f(pr[i]);
        s += v[i];
        s2 += v[i] * v[i];
    }
    for (int off = 32; off; off >>= 1) {
        s  += __shfl_down(s, off, 64);
        s2 += __shfl_down(s2, off, 64);
    }
    __shared__ float red[8];
    if ((t & 63) == 0) { red[(t >> 6) * 2] = s; red[(t >> 6) * 2 + 1] = s2; }
    __syncthreads();
    float ts  = red[0] + red[2] + red[4] + red[6];
    float ts2 = red[1] + red[3] + red[5] + red[7];
    float mu  = ts * (1.0f / 2048.0f);
    float var = ts2 * (1.0f / 2048.0f) - mu * mu;
    float inv = rsqrtf(var + 1e-5f);
    uint16_t outv[8];
    for (int i = 0; i < 8; i++) {
        float y = (v[i] - mu) * inv * Gm[t * 8 + i] + Bt[t * 8 + i];
        outv[i] = f2bf(y);
    }
    u32x4 ov;
    __builtin_memcpy(&ov, outv, 16);
    *(u32x4*)(Y + (size_t)row * 2048 + t * 8) = ov;
}

// ---------------------------------------------------------------------------
extern "C" void kernel_launch(void* const* d_in, const int* in_sizes, int n_in,
                              void* d_out, int out_size, void* d_ws, size_t ws_size,
                              hipStream_t stream)
{
    const float* x  = (const float*)d_in[0];
    const float* Wk = (const float*)d_in[1];
    const float* Wv = (const float*)d_in[2];
    const float* Wo = (const float*)d_in[3];
    const float* lg = (const float*)d_in[4];
    const float* lb = (const float*)d_in[5];
    const float* W0 = (const float*)d_in[6];
    float* out = (float*)d_out;

    const size_t NTOK = 8192, HID = 2048;
    // ws (bf16 elems): xb(->kp after GEMMs) | wbuf | kb | vb | kt | vt  ~176 MB
    uint16_t* xb   = (uint16_t*)d_ws;          // 8192*2048; reused as kp
    uint16_t* wbuf = xb + NTOK * HID;          // 2048*2048
    uint16_t* kb   = wbuf + HID * HID;         // 8192*2048
    uint16_t* vb   = kb + NTOK * HID;          // 8192*2048
    uint16_t* kt   = vb + NTOK * HID;          // 8192*2048
    uint16_t* vt   = kt + NTOK * HID;          // 8192*2048
    uint16_t* kp   = xb;                       // xb dead after both proj GEMMs
    uint16_t* ob   = (uint16_t*)d_out;         // scan out parks in d_out bytes
    uint16_t* lnb  = kb;                       // kb dead after repack

    dim3 grid(16, 64), blk(256);
    const int nX4 = (int)(NTOK * HID / 4), nW4 = (int)(HID * HID / 4);

    cvt_bf16<<<4096, 256, 0, stream>>>(x, xb, nX4);
    cvt_bf16<<<4096, 256, 0, stream>>>(Wk, wbuf, nW4);
    gemm_bt<false><<<grid, blk, 0, stream>>>(xb, wbuf, kb, nullptr, 8192, 2048, 2048);
    cvt_bf16<<<4096, 256, 0, stream>>>(Wv, wbuf, nW4);
    gemm_bt<false><<<grid, blk, 0, stream>>>(xb, wbuf, vb, nullptr, 8192, 2048, 2048);
    repack<<<8192, 64, 0, stream>>>(kb, vb, kp, kt, vt);
    ttt_scan<<<256, 64, 0, stream>>>(kp, kt, vt, W0, ob);
    ln_kernel<<<8192, 256, 0, stream>>>(ob, lg, lb, lnb);
    cvt_bf16<<<4096, 256, 0, stream>>>(Wo, wbuf, nW4);
    gemm_bt<true><<<grid, blk, 0, stream>>>(lnb, wbuf, out, x, 8192, 2048, 2048);
}

// Round 2
// 631.341 us; speedup vs baseline: 1.1225x; 1.0810x over previous
//
#include <hip/hip_runtime.h>
#include <cstdint>
#include <cstddef>

typedef __attribute__((ext_vector_type(4))) float    f32x4;
typedef __attribute__((ext_vector_type(8))) __bf16   bf16x8;
typedef __attribute__((ext_vector_type(4))) short    s16x4;
typedef __attribute__((ext_vector_type(4))) uint32_t u32x4;
typedef __attribute__((ext_vector_type(2))) uint32_t u32x2;

__device__ __forceinline__ float bf2f(uint16_t h) {
    uint32_t u = ((uint32_t)h) << 16;
    return __builtin_bit_cast(float, u);
}
__device__ __forceinline__ uint16_t f2bf(float f) {
    uint32_t u = __builtin_bit_cast(uint32_t, f);
    uint32_t r = (u + 0x7fffu + ((u >> 16) & 1u)) >> 16;  // RNE
    return (uint16_t)r;
}
// native HW convert (RNE) — for hot loops
__device__ __forceinline__ uint16_t f2bf_fast(float f) {
    __bf16 h = (__bf16)f;
    return __builtin_bit_cast(uint16_t, h);
}

__device__ __forceinline__ f32x4 mfma32(bf16x8 a, bf16x8 b, f32x4 c) {
    return __builtin_amdgcn_mfma_f32_16x16x32_bf16(a, b, c, 0, 0, 0);
}
__device__ __forceinline__ f32x4 mfma16(s16x4 a, s16x4 b, f32x4 c) {
    return __builtin_amdgcn_mfma_f32_16x16x16bf16_1k(a, b, c, 0, 0, 0);
}

// async global->LDS, 16B per lane (GEMM staging)
__device__ __forceinline__ void gload16(const void* g, void* l) {
    __builtin_amdgcn_global_load_lds(
        (const __attribute__((address_space(1))) uint32_t*)g,
        (__attribute__((address_space(3))) uint32_t*)l, 16, 0, 0);
}

// ---------------------------------------------------------------------------
// fp32 -> bf16 elementwise, 4 elems/thread/iter, grid-stride
// ---------------------------------------------------------------------------
__global__ __launch_bounds__(256) void cvt_bf16(
    const float* __restrict__ s, uint16_t* __restrict__ d, int n4)
{
    int i = blockIdx.x * 256 + threadIdx.x;
    const int stride = gridDim.x * 256;
    for (; i < n4; i += stride) {
        f32x4 v = ((const f32x4*)s)[i];
        u32x2 p;
        p[0] = (uint32_t)f2bf(v[0]) | ((uint32_t)f2bf(v[1]) << 16);
        p[1] = (uint32_t)f2bf(v[2]) | ((uint32_t)f2bf(v[3]) << 16);
        ((u32x2*)d)[i] = p;
    }
}

// ---------------------------------------------------------------------------
// C[M,N] = A[M,K] @ B[N,K]^T, bf16 in, fp32 acc.  (m97 structure)
// ---------------------------------------------------------------------------
template <bool F32OUT>
__global__ __launch_bounds__(256) void gemm_bt(
    const uint16_t* __restrict__ A, const uint16_t* __restrict__ B,
    void* __restrict__ Cv, const float* __restrict__ R,
    int M, int N, int K)
{
    __shared__ __align__(16) uint16_t lA[128 * 32];
    __shared__ __align__(16) uint16_t lB[128 * 32];
    const int tid = threadIdx.x;
    const int wv = tid >> 6, ln = tid & 63;
    const int l15 = ln & 15, q = ln >> 4;
    const int m0 = blockIdx.y * 128, n0 = blockIdx.x * 128;
    const int wm = (wv >> 1) * 64, wn = (wv & 1) * 64;

    const uint16_t* ga = A + (size_t)(m0 + wv * 32 + (ln >> 2)) * K + (ln & 3) * 8;
    const uint16_t* gb = B + (size_t)(n0 + wv * 32 + (ln >> 2)) * K + (ln & 3) * 8;
    uint16_t* la = lA + (wv * 32) * 32;
    uint16_t* lb = lB + (wv * 32) * 32;

    f32x4 acc[4][4];
    for (int i = 0; i < 4; i++)
        for (int j = 0; j < 4; j++)
            acc[i][j] = (f32x4){0.f, 0.f, 0.f, 0.f};

    for (int kt = 0; kt < K; kt += 32) {
        gload16(ga + kt, la);
        gload16(ga + (size_t)16 * K + kt, la + 16 * 32);
        gload16(gb + kt, lb);
        gload16(gb + (size_t)16 * K + kt, lb + 16 * 32);
        __syncthreads();

        bf16x8 af[4], bfv[4];
        for (int mt = 0; mt < 4; mt++)
            af[mt] = __builtin_bit_cast(bf16x8,
                *(const u32x4*)(lA + (wm + mt * 16 + l15) * 32 + q * 8));
        for (int nt = 0; nt < 4; nt++)
            bfv[nt] = __builtin_bit_cast(bf16x8,
                *(const u32x4*)(lB + (wn + nt * 16 + l15) * 32 + q * 8));
        for (int mt = 0; mt < 4; mt++)
            for (int nt = 0; nt < 4; nt++)
                acc[mt][nt] = mfma32(af[mt], bfv[nt], acc[mt][nt]);
        __syncthreads();
    }

    for (int mt = 0; mt < 4; mt++)
        for (int nt = 0; nt < 4; nt++)
            for (int r = 0; r < 4; r++) {
                int row = m0 + wm + mt * 16 + q * 4 + r;
                int col = n0 + wn + nt * 16 + l15;
                size_t idx = (size_t)row * N + col;
                float v = acc[mt][nt][r];
                if (F32OUT) {
                    ((float*)Cv)[idx] = v + R[idx];
                } else {
                    ((uint16_t*)Cv)[idx] = f2bf(v);
                }
            }
}

// ---------------------------------------------------------------------------
// repack + fused RoPE: per (b,h,c) emit contiguous tiles
//   kp[g][m16][d128], kt[g][d128][m16], vt[g][e128][m16];  g=((b*16)+h)*128+c
// ---------------------------------------------------------------------------
__global__ __launch_bounds__(64) void repack(
    const uint16_t* __restrict__ kb, const uint16_t* __restrict__ vb,
    uint16_t* __restrict__ kp, uint16_t* __restrict__ kt,
    uint16_t* __restrict__ vt)
{
    const int g = blockIdx.x;
    const int c = g & 127, h = (g >> 7) & 15, b = g >> 11;
    const int ln = threadIdx.x;
    const int m = ln >> 2, cb = (ln & 3) * 32;
    const size_t tok = (size_t)b * 2048 + c * 16 + m;
    const int s = c * 16 + m;
    const uint16_t* krow = kb + tok * 2048 + h * 128;
    const uint16_t* vrow = vb + tok * 2048 + h * 128;

    u32x4 kraw[4], praw[4], vraw[4];
    for (int i = 0; i < 4; i++) {
        kraw[i] = *(const u32x4*)(krow + cb + 8 * i);
        praw[i] = *(const u32x4*)(krow + (cb ^ 64) + 8 * i);
        vraw[i] = *(const u32x4*)(vrow + cb + 8 * i);
    }
    const uint16_t* ku = (const uint16_t*)kraw;
    const uint16_t* pu = (const uint16_t*)praw;
    const uint16_t* vu = (const uint16_t*)vraw;

    uint16_t ko[32];
    for (int j = 0; j < 32; j++) {
        int col = cb + j;
        int p = col & 63;
        float invf = exp2f((float)p * (-13.287712379549449f / 64.0f));
        float a = (float)s * invf;
        float sn, cs;
        __sincosf(a, &sn, &cs);
        float u1 = bf2f(ku[j]), u2 = bf2f(pu[j]);
        float o = (col < 64) ? (u1 * cs - u2 * sn) : (u1 * cs + u2 * sn);
        ko[j] = f2bf(o);
    }

    uint16_t* kpg = kp + (size_t)g * 2048;
    uint16_t* ktg = kt + (size_t)g * 2048;
    uint16_t* vtg = vt + (size_t)g * 2048;
    for (int i = 0; i < 4; i++) {
        u32x4 pk;
        uint32_t* pw = (uint32_t*)&pk;
        for (int w = 0; w < 4; w++)
            pw[w] = (uint32_t)ko[8 * i + 2 * w] | ((uint32_t)ko[8 * i + 2 * w + 1] << 16);
        *(u32x4*)(kpg + m * 128 + cb + 8 * i) = pk;
    }
    for (int j = 0; j < 32; j++) {
        ktg[(cb + j) * 16 + m] = ko[j];
        vtg[(cb + j) * 16 + m] = vu[j];
    }
}

// ---------------------------------------------------------------------------
// TTT scan v3: one single-wave block per (b,h,e-slice16) -> 512 blocks,
// 2 waves/CU (stall hiding). Slice s of group g is block (s*64 + g): all 8
// siblings share bid%8 -> same XCD -> kp/kt tiles L2-shared.
// No LDS staging, no s_barrier, and NO per-step lgkmcnt drain: same-wave DS
// ops are serviced in order, so the W-shadow write->read RAW hazard needs no
// waitcnt (compiler still waits for its own read data). LDS holds only the
// bf16 W-shadow [e16][d128+8]. W master fp32 in regs. MFMA accumulate chains
// split 2+2 to halve dependency depth.
// pred = k@W; G = k k^T; errS = (v-pred)/1024; W += k^T@errS; out = pred+G@errS.
// ---------------------------------------------------------------------------
__global__ __launch_bounds__(64, 1) void ttt_scan(
    const uint16_t* __restrict__ kp, const uint16_t* __restrict__ kt,
    const uint16_t* __restrict__ vt, const float* __restrict__ W0,
    uint16_t* __restrict__ O)
{
    __shared__ __align__(16) uint16_t wbp[16 * 136];   // [e][d] +8 pad

    const int bid = blockIdx.x;
    const int g  = bid & 63;            // (b,h) group
    const int e0 = (bid >> 6) * 16;     // e-slice; siblings bid+64*s
    const int h = g & 15, b = g >> 4;
    const int ln = threadIdx.x;
    const int l15 = ln & 15, q = ln >> 4;

    // W[mt] reg r holds W[d = 16mt+4q+r][e = e0+l15]  (fp32 master)
    f32x4 W[8];
    {
        const float* w0p = W0 + (size_t)g * 128 * 128;
        #pragma unroll
        for (int mt = 0; mt < 8; mt++)
            for (int r = 0; r < 4; r++)
                W[mt][r] = w0p[(size_t)(16 * mt + 4 * q + r) * 128 + e0 + l15];
    }
    #pragma unroll
    for (int mt = 0; mt < 8; mt++) {
        uint32_t p0 = (uint32_t)f2bf_fast(W[mt][0]) | ((uint32_t)f2bf_fast(W[mt][1]) << 16);
        uint32_t p1 = (uint32_t)f2bf_fast(W[mt][2]) | ((uint32_t)f2bf_fast(W[mt][3]) << 16);
        u32x2 pp; pp[0] = p0; pp[1] = p1;
        *(u32x2*)(wbp + l15 * 136 + 16 * mt + 4 * q) = pp;
    }

    const uint16_t* kpw = kp + (size_t)g * 128 * 2048;
    const uint16_t* ktw = kt + (size_t)g * 128 * 2048;
    const uint16_t* vtw = vt + (size_t)g * 128 * 2048;
    uint16_t*     obase = O  + (size_t)b * 2048 * 2048 + h * 128 + e0;

    // fragment prefetch (direct from global; tiles are L2-hot on this XCD)
    auto loadset = [&](int c, u32x4* afr, u32x2* ktr, u32x2* vvr) {
        const uint16_t* kc = kpw + (size_t)c * 2048;
        const uint16_t* tc = ktw + (size_t)c * 2048;
        const uint16_t* vc = vtw + (size_t)c * 2048;
        #pragma unroll
        for (int ks = 0; ks < 4; ks++)
            afr[ks] = *(const u32x4*)(kc + l15 * 128 + ks * 32 + q * 8);
        #pragma unroll
        for (int mt = 0; mt < 8; mt++)
            ktr[mt] = *(const u32x2*)(tc + (16 * mt + l15) * 16 + 4 * q);
        vvr[0] = *(const u32x2*)(vc + (e0 + l15) * 16 + 4 * q);
    };

    auto step = [&](int c, const u32x4* afr, const u32x2* ktr, const u32x2* vvr) {
        const int s0 = c * 16;

        // pred and G = k k^T; B-operand from W-shadow; 2+2 split chains
        f32x4 accA = (f32x4){0.f, 0.f, 0.f, 0.f};
        f32x4 accB = (f32x4){0.f, 0.f, 0.f, 0.f};
        f32x4 gacA = (f32x4){0.f, 0.f, 0.f, 0.f};
        f32x4 gacB = (f32x4){0.f, 0.f, 0.f, 0.f};
        #pragma unroll
        for (int ks = 0; ks < 4; ks++) {
            bf16x8 a = __builtin_bit_cast(bf16x8, afr[ks]);
            bf16x8 bb = __builtin_bit_cast(bf16x8,
                *(const u32x4*)(wbp + l15 * 136 + ks * 32 + q * 8));
            if (ks & 1) { accB = mfma32(a, bb, accB); gacB = mfma32(a, a, gacB); }
            else        { accA = mfma32(a, bb, accA); gacA = mfma32(a, a, gacA); }
        }
        f32x4 acc, gacc;
        #pragma unroll
        for (int r = 0; r < 4; r++) { acc[r] = accA[r] + accB[r]; gacc[r] = gacA[r] + gacB[r]; }

        // errS = (v - pred)/1024, already in 16x16x16 A/B operand layout
        s16x4 vv = __builtin_bit_cast(s16x4, vvr[0]);
        s16x4 es, gf;
        #pragma unroll
        for (int r = 0; r < 4; r++) {
            es[r] = (short)f2bf_fast((bf2f((uint16_t)vv[r]) - acc[r]) * (1.0f / 1024.0f));
            gf[r] = (short)f2bf_fast(gacc[r]);
        }

        // out = pred + G @ errS
        f32x4 o = mfma16(gf, es, acc);

        // W update: W += k^T @ errS
        #pragma unroll
        for (int mt = 0; mt < 8; mt++) {
            s16x4 kf = __builtin_bit_cast(s16x4, ktr[mt]);
            W[mt] = mfma16(kf, es, W[mt]);
        }

        // store out chunk (fire-and-forget)
        #pragma unroll
        for (int r = 0; r < 4; r++)
            obase[(size_t)(s0 + 4 * q + r) * 2048 + l15] = f2bf_fast(o[r]);

        // rewrite shadow (same-wave in-order DS: no waitcnt/barrier needed;
        // alias analysis keeps read->write->read program order)
        #pragma unroll
        for (int mt = 0; mt < 8; mt++) {
            uint32_t p0 = (uint32_t)f2bf_fast(W[mt][0]) | ((uint32_t)f2bf_fast(W[mt][1]) << 16);
            uint32_t p1 = (uint32_t)f2bf_fast(W[mt][2]) | ((uint32_t)f2bf_fast(W[mt][3]) << 16);
            u32x2 pp; pp[0] = p0; pp[1] = p1;
            *(u32x2*)(wbp + l15 * 136 + 16 * mt + 4 * q) = pp;
        }
    };

    u32x4 afA[4], afB[4];
    u32x2 ktA[8], ktB[8];
    u32x2 vvA[1], vvB[1];
    loadset(0, afA, ktA, vvA);
    loadset(1, afB, ktB, vvB);

    for (int c = 0; c < 128; c += 2) {
        step(c, afA, ktA, vvA);
        if (c < 126) loadset(c + 2, afA, ktA, vvA);
        step(c + 1, afB, ktB, vvB);
        if (c < 126) loadset(c + 3, afB, ktB, vvB);
    }
}

// ---------------------------------------------------------------------------
// LayerNorm over rows of 2048 (biased var), * g + b; X bf16, g/b fp32, Y bf16
// ---------------------------------------------------------------------------
__global__ __launch_bounds__(256) void ln_kernel(
    const uint16_t* __restrict__ X, const float* __restrict__ Gm,
    const float* __restrict__ Bt, uint16_t* __restrict__ Y)
{
    const int row = blockIdx.x, t = threadIdx.x;
    const uint16_t* xr = X + (size_t)row * 2048 + t * 8;
    u32x4 raw = *(const u32x4*)xr;
    const uint16_t* pr = (const uint16_t*)&raw;
    float v[8];
    float s = 0.f, s2 = 0.f;
    for (int i = 0; i < 8; i++) {
        v[i] = bf2f(pr[i]);
        s += v[i];
        s2 += v[i] * v[i];
    }
    for (int off = 32; off; off >>= 1) {
        s  += __shfl_down(s, off, 64);
        s2 += __shfl_down(s2, off, 64);
    }
    __shared__ float red[8];
    if ((t & 63) == 0) { red[(t >> 6) * 2] = s; red[(t >> 6) * 2 + 1] = s2; }
    __syncthreads();
    float ts  = red[0] + red[2] + red[4] + red[6];
    float ts2 = red[1] + red[3] + red[5] + red[7];
    float mu  = ts * (1.0f / 2048.0f);
    float var = ts2 * (1.0f / 2048.0f) - mu * mu;
    float inv = rsqrtf(var + 1e-5f);
    uint16_t outv[8];
    for (int i = 0; i < 8; i++) {
        float y = (v[i] - mu) * inv * Gm[t * 8 + i] + Bt[t * 8 + i];
        outv[i] = f2bf(y);
    }
    u32x4 ov;
    __builtin_memcpy(&ov, outv, 16);
    *(u32x4*)(Y + (size_t)row * 2048 + t * 8) = ov;
}

// ---------------------------------------------------------------------------
extern "C" void kernel_launch(void* const* d_in, const int* in_sizes, int n_in,
                              void* d_out, int out_size, void* d_ws, size_t ws_size,
                              hipStream_t stream)
{
    const float* x  = (const float*)d_in[0];
    const float* Wk = (const float*)d_in[1];
    const float* Wv = (const float*)d_in[2];
    const float* Wo = (const float*)d_in[3];
    const float* lg = (const float*)d_in[4];
    const float* lb = (const float*)d_in[5];
    const float* W0 = (const float*)d_in[6];
    float* out = (float*)d_out;

    const size_t NTOK = 8192, HID = 2048;
    // ws (bf16 elems): xb(->kp after GEMMs) | wbuf | kb | vb | kt | vt  ~176 MB
    uint16_t* xb   = (uint16_t*)d_ws;          // 8192*2048; reused as kp
    uint16_t* wbuf = xb + NTOK * HID;          // 2048*2048
    uint16_t* kb   = wbuf + HID * HID;         // 8192*2048
    uint16_t* vb   = kb + NTOK * HID;          // 8192*2048
    uint16_t* kt   = vb + NTOK * HID;          // 8192*2048
    uint16_t* vt   = kt + NTOK * HID;          // 8192*2048
    uint16_t* kp   = xb;                       // xb dead after both proj GEMMs
    uint16_t* ob   = (uint16_t*)d_out;         // scan out parks in d_out bytes
    uint16_t* lnb  = kb;                       // kb dead after repack

    dim3 grid(16, 64), blk(256);
    const int nX4 = (int)(NTOK * HID / 4), nW4 = (int)(HID * HID / 4);

    cvt_bf16<<<4096, 256, 0, stream>>>(x, xb, nX4);
    cvt_bf16<<<4096, 256, 0, stream>>>(Wk, wbuf, nW4);
    gemm_bt<false><<<grid, blk, 0, stream>>>(xb, wbuf, kb, nullptr, 8192, 2048, 2048);
    cvt_bf16<<<4096, 256, 0, stream>>>(Wv, wbuf, nW4);
    gemm_bt<false><<<grid, blk, 0, stream>>>(xb, wbuf, vb, nullptr, 8192, 2048, 2048);
    repack<<<8192, 64, 0, stream>>>(kb, vb, kp, kt, vt);
    ttt_scan<<<512, 64, 0, stream>>>(kp, kt, vt, W0, ob);
    ln_kernel<<<8192, 256, 0, stream>>>(ob, lg, lb, lnb);
    cvt_bf16<<<4096, 256, 0, stream>>>(Wo, wbuf, nW4);
    gemm_bt<true><<<grid, blk, 0, stream>>>(lnb, wbuf, out, x, 8192, 2048, 2048);
}

// Round 4
// 538.587 us; speedup vs baseline: 1.3158x; 1.1722x over previous
//
#include <hip/hip_runtime.h>
#include <cstdint>
#include <cstddef>

typedef __attribute__((ext_vector_type(4))) float    f32x4;
typedef __attribute__((ext_vector_type(8))) __bf16   bf16x8;
typedef __attribute__((ext_vector_type(4))) short    s16x4;
typedef __attribute__((ext_vector_type(4))) uint32_t u32x4;
typedef __attribute__((ext_vector_type(2))) uint32_t u32x2;

__device__ __forceinline__ float bf2f(uint16_t h) {
    uint32_t u = ((uint32_t)h) << 16;
    return __builtin_bit_cast(float, u);
}
__device__ __forceinline__ uint16_t f2bf(float f) {
    uint32_t u = __builtin_bit_cast(uint32_t, f);
    uint32_t r = (u + 0x7fffu + ((u >> 16) & 1u)) >> 16;  // RNE
    return (uint16_t)r;
}
// native HW convert (RNE) — for hot loops
__device__ __forceinline__ uint16_t f2bf_fast(float f) {
    __bf16 h = (__bf16)f;
    return __builtin_bit_cast(uint16_t, h);
}

__device__ __forceinline__ f32x4 mfma32(bf16x8 a, bf16x8 b, f32x4 c) {
    return __builtin_amdgcn_mfma_f32_16x16x32_bf16(a, b, c, 0, 0, 0);
}
__device__ __forceinline__ f32x4 mfma16(s16x4 a, s16x4 b, f32x4 c) {
    return __builtin_amdgcn_mfma_f32_16x16x16bf16_1k(a, b, c, 0, 0, 0);
}

// async global->LDS, 16B per lane (GEMM staging)
__device__ __forceinline__ void gload16(const void* g, void* l) {
    __builtin_amdgcn_global_load_lds(
        (const __attribute__((address_space(1))) uint32_t*)g,
        (__attribute__((address_space(3))) uint32_t*)l, 16, 0, 0);
}

// ---------------------------------------------------------------------------
// fp32 -> bf16 elementwise, 4 elems/thread/iter, grid-stride
// ---------------------------------------------------------------------------
__global__ __launch_bounds__(256) void cvt_bf16(
    const float* __restrict__ s, uint16_t* __restrict__ d, int n4)
{
    int i = blockIdx.x * 256 + threadIdx.x;
    const int stride = gridDim.x * 256;
    for (; i < n4; i += stride) {
        f32x4 v = ((const f32x4*)s)[i];
        u32x2 p;
        p[0] = (uint32_t)f2bf(v[0]) | ((uint32_t)f2bf(v[1]) << 16);
        p[1] = (uint32_t)f2bf(v[2]) | ((uint32_t)f2bf(v[3]) << 16);
        ((u32x2*)d)[i] = p;
    }
}

// ---------------------------------------------------------------------------
// C[M,N] = A[M,K] @ B[N,K]^T, bf16 in, fp32 acc.
// 256x256 tile, BK=64, 8 waves (2Mx4N), 512 thr, double-buffered LDS.
// Sync = single __syncthreads() per K-tile (full drain) — the minimum-2-phase
// recipe; correct by construction (stage(t+1) -> slot s^1 issued BEFORE the
// MFMAs so HBM latency overlaps compute; slot s overwritten only after the
// barrier at which all waves' slot-s ds_reads retired).
// LDS swizzle: element (row,k) at row*64 + (k ^ ((row&7)*8)); realized as
// linear gload_lds dest + inverse-swizzled per-lane GLOBAL source column,
// swizzled ds_read offset (both-sides-or-neither, rule #21).
// ---------------------------------------------------------------------------
template <bool F32OUT>
__global__ __launch_bounds__(512, 2) void gemm256(
    const uint16_t* __restrict__ A, const uint16_t* __restrict__ B,
    void* __restrict__ Cv, const float* __restrict__ R,
    int M, int N, int K)
{
    __shared__ __align__(16) uint16_t lA[2][256 * 64];
    __shared__ __align__(16) uint16_t lB[2][256 * 64];

    const int tid = threadIdx.x;
    const int w = tid >> 6, ln = tid & 63;
    const int l15 = ln & 15, q = ln >> 4;
    const int wm = w >> 2, wn = w & 3;            // 2 x 4 wave grid
    const int m0 = blockIdx.y * 256, n0 = blockIdx.x * 256;

    // staging: wave w owns rows w*32..w*32+31; 4 issues of 8 rows each;
    // lane l -> row += (l>>3), 16B granule (l&7); global source column
    // pre-swizzled so LDS content is row*64 + (k ^ ((row&7)*8)).
    const int srow = w * 32 + (ln >> 3);
    const int scol = ((ln & 7) ^ (ln >> 3)) * 8;
    const uint16_t* gA = A + (size_t)(m0 + srow) * K + scol;
    const uint16_t* gB = B + (size_t)(n0 + srow) * K + scol;

    f32x4 acc[8][4];
    #pragma unroll
    for (int i = 0; i < 8; i++)
        for (int j = 0; j < 4; j++)
            acc[i][j] = (f32x4){0.f, 0.f, 0.f, 0.f};

    // per-thread fragment read offsets (elements)
    const int xs  = (l15 & 7) * 8;
    const int aro = (wm * 128 + l15) * 64;        // A row base (mt adds 16*64)
    const int bro = (wn * 64 + l15) * 64;         // B row base (nt adds 16*64)
    const int k0o = (q * 8) ^ xs;                 // ks=0 swizzled offset
    const int k1o = (32 + q * 8) ^ xs;            // ks=1 swizzled offset

    auto stage = [&](int t) {
        const int s = t & 1;
        const int kt = t * 64;
        #pragma unroll
        for (int i = 0; i < 4; i++)
            gload16(gA + (size_t)(i * 8) * K + kt, lA[s] + (w * 32 + i * 8) * 64);
        #pragma unroll
        for (int i = 0; i < 4; i++)
            gload16(gB + (size_t)(i * 8) * K + kt, lB[s] + (w * 32 + i * 8) * 64);
    };

    const int ntk = K >> 6;                       // K-tiles of 64
    stage(0);
    __syncthreads();

    for (int t = 0; t < ntk; ++t) {
        const int s = t & 1;
        if (t + 1 < ntk) stage(t + 1);            // -> slot s^1, lands by barrier

        const uint16_t* As = lA[s];
        const uint16_t* Bs = lB[s];

        bf16x8 a0[8], b0[4];
        #pragma unroll
        for (int mt = 0; mt < 8; mt++)
            a0[mt] = __builtin_bit_cast(bf16x8,
                *(const u32x4*)(As + aro + mt * 1024 + k0o));
        #pragma unroll
        for (int nt2 = 0; nt2 < 4; nt2++)
            b0[nt2] = __builtin_bit_cast(bf16x8,
                *(const u32x4*)(Bs + bro + nt2 * 1024 + k0o));
        #pragma unroll
        for (int mt = 0; mt < 8; mt++)
            #pragma unroll
            for (int nt2 = 0; nt2 < 4; nt2++)
                acc[mt][nt2] = mfma32(a0[mt], b0[nt2], acc[mt][nt2]);

        bf16x8 a1[8], b1[4];
        #pragma unroll
        for (int mt = 0; mt < 8; mt++)
            a1[mt] = __builtin_bit_cast(bf16x8,
                *(const u32x4*)(As + aro + mt * 1024 + k1o));
        #pragma unroll
        for (int nt2 = 0; nt2 < 4; nt2++)
            b1[nt2] = __builtin_bit_cast(bf16x8,
                *(const u32x4*)(Bs + bro + nt2 * 1024 + k1o));
        #pragma unroll
        for (int mt = 0; mt < 8; mt++)
            #pragma unroll
            for (int nt2 = 0; nt2 < 4; nt2++)
                acc[mt][nt2] = mfma32(a1[mt], b1[nt2], acc[mt][nt2]);

        __syncthreads();   // tile t+1 landed; slot-s reads retired everywhere
    }

    #pragma unroll
    for (int mt = 0; mt < 8; mt++)
        #pragma unroll
        for (int nt2 = 0; nt2 < 4; nt2++)
            #pragma unroll
            for (int r = 0; r < 4; r++) {
                int row = m0 + wm * 128 + mt * 16 + q * 4 + r;
                int col = n0 + wn * 64 + nt2 * 16 + l15;
                size_t idx = (size_t)row * N + col;
                float v = acc[mt][nt2][r];
                if (F32OUT) {
                    ((float*)Cv)[idx] = v + R[idx];
                } else {
                    ((uint16_t*)Cv)[idx] = f2bf(v);
                }
            }
}

// ---------------------------------------------------------------------------
// repack + fused RoPE: per (b,h,c) emit contiguous tiles
//   kp[g][m16][d128], kt[g][d128][m16], vt[g][e128][m16];  g=((b*16)+h)*128+c
// ---------------------------------------------------------------------------
__global__ __launch_bounds__(64) void repack(
    const uint16_t* __restrict__ kb, const uint16_t* __restrict__ vb,
    uint16_t* __restrict__ kp, uint16_t* __restrict__ kt,
    uint16_t* __restrict__ vt)
{
    const int g = blockIdx.x;
    const int c = g & 127, h = (g >> 7) & 15, b = g >> 11;
    const int ln = threadIdx.x;
    const int m = ln >> 2, cb = (ln & 3) * 32;
    const size_t tok = (size_t)b * 2048 + c * 16 + m;
    const int s = c * 16 + m;
    const uint16_t* krow = kb + tok * 2048 + h * 128;
    const uint16_t* vrow = vb + tok * 2048 + h * 128;

    u32x4 kraw[4], praw[4], vraw[4];
    for (int i = 0; i < 4; i++) {
        kraw[i] = *(const u32x4*)(krow + cb + 8 * i);
        praw[i] = *(const u32x4*)(krow + (cb ^ 64) + 8 * i);
        vraw[i] = *(const u32x4*)(vrow + cb + 8 * i);
    }
    const uint16_t* ku = (const uint16_t*)kraw;
    const uint16_t* pu = (const uint16_t*)praw;
    const uint16_t* vu = (const uint16_t*)vraw;

    uint16_t ko[32];
    for (int j = 0; j < 32; j++) {
        int col = cb + j;
        int p = col & 63;
        float invf = exp2f((float)p * (-13.287712379549449f / 64.0f));
        float a = (float)s * invf;
        float sn, cs;
        __sincosf(a, &sn, &cs);
        float u1 = bf2f(ku[j]), u2 = bf2f(pu[j]);
        float o = (col < 64) ? (u1 * cs - u2 * sn) : (u1 * cs + u2 * sn);
        ko[j] = f2bf(o);
    }

    uint16_t* kpg = kp + (size_t)g * 2048;
    uint16_t* ktg = kt + (size_t)g * 2048;
    uint16_t* vtg = vt + (size_t)g * 2048;
    for (int i = 0; i < 4; i++) {
        u32x4 pk;
        uint32_t* pw = (uint32_t*)&pk;
        for (int w = 0; w < 4; w++)
            pw[w] = (uint32_t)ko[8 * i + 2 * w] | ((uint32_t)ko[8 * i + 2 * w + 1] << 16);
        *(u32x4*)(kpg + m * 128 + cb + 8 * i) = pk;
    }
    for (int j = 0; j < 32; j++) {
        ktg[(cb + j) * 16 + m] = ko[j];
        vtg[(cb + j) * 16 + m] = vu[j];
    }
}

// ---------------------------------------------------------------------------
// TTT scan v3: one single-wave block per (b,h,e-slice16) -> 512 blocks,
// 2 waves/CU. Siblings share bid%8 -> same XCD -> kp/kt tiles L2-shared.
// LDS holds only the bf16 W-shadow [e16][d128+8]; W master fp32 in regs.
// ---------------------------------------------------------------------------
__global__ __launch_bounds__(64, 1) void ttt_scan(
    const uint16_t* __restrict__ kp, const uint16_t* __restrict__ kt,
    const uint16_t* __restrict__ vt, const float* __restrict__ W0,
    uint16_t* __restrict__ O)
{
    __shared__ __align__(16) uint16_t wbp[16 * 136];   // [e][d] +8 pad

    const int bid = blockIdx.x;
    const int g  = bid & 63;            // (b,h) group
    const int e0 = (bid >> 6) * 16;     // e-slice; siblings bid+64*s
    const int h = g & 15, b = g >> 4;
    const int ln = threadIdx.x;
    const int l15 = ln & 15, q = ln >> 4;

    // W[mt] reg r holds W[d = 16mt+4q+r][e = e0+l15]  (fp32 master)
    f32x4 W[8];
    {
        const float* w0p = W0 + (size_t)g * 128 * 128;
        #pragma unroll
        for (int mt = 0; mt < 8; mt++)
            for (int r = 0; r < 4; r++)
                W[mt][r] = w0p[(size_t)(16 * mt + 4 * q + r) * 128 + e0 + l15];
    }
    #pragma unroll
    for (int mt = 0; mt < 8; mt++) {
        uint32_t p0 = (uint32_t)f2bf_fast(W[mt][0]) | ((uint32_t)f2bf_fast(W[mt][1]) << 16);
        uint32_t p1 = (uint32_t)f2bf_fast(W[mt][2]) | ((uint32_t)f2bf_fast(W[mt][3]) << 16);
        u32x2 pp; pp[0] = p0; pp[1] = p1;
        *(u32x2*)(wbp + l15 * 136 + 16 * mt + 4 * q) = pp;
    }

    const uint16_t* kpw = kp + (size_t)g * 128 * 2048;
    const uint16_t* ktw = kt + (size_t)g * 128 * 2048;
    const uint16_t* vtw = vt + (size_t)g * 128 * 2048;
    uint16_t*     obase = O  + (size_t)b * 2048 * 2048 + h * 128 + e0;

    // fragment prefetch (direct from global; tiles are L2-hot on this XCD)
    auto loadset = [&](int c, u32x4* afr, u32x2* ktr, u32x2* vvr) {
        const uint16_t* kc = kpw + (size_t)c * 2048;
        const uint16_t* tc = ktw + (size_t)c * 2048;
        const uint16_t* vc = vtw + (size_t)c * 2048;
        #pragma unroll
        for (int ks = 0; ks < 4; ks++)
            afr[ks] = *(const u32x4*)(kc + l15 * 128 + ks * 32 + q * 8);
        #pragma unroll
        for (int mt = 0; mt < 8; mt++)
            ktr[mt] = *(const u32x2*)(tc + (16 * mt + l15) * 16 + 4 * q);
        vvr[0] = *(const u32x2*)(vc + (e0 + l15) * 16 + 4 * q);
    };

    auto step = [&](int c, const u32x4* afr, const u32x2* ktr, const u32x2* vvr) {
        const int s0 = c * 16;

        // pred and G = k k^T; B-operand from W-shadow; 2+2 split chains
        f32x4 accA = (f32x4){0.f, 0.f, 0.f, 0.f};
        f32x4 accB = (f32x4){0.f, 0.f, 0.f, 0.f};
        f32x4 gacA = (f32x4){0.f, 0.f, 0.f, 0.f};
        f32x4 gacB = (f32x4){0.f, 0.f, 0.f, 0.f};
        #pragma unroll
        for (int ks = 0; ks < 4; ks++) {
            bf16x8 a = __builtin_bit_cast(bf16x8, afr[ks]);
            bf16x8 bb = __builtin_bit_cast(bf16x8,
                *(const u32x4*)(wbp + l15 * 136 + ks * 32 + q * 8));
            if (ks & 1) { accB = mfma32(a, bb, accB); gacB = mfma32(a, a, gacB); }
            else        { accA = mfma32(a, bb, accA); gacA = mfma32(a, a, gacA); }
        }
        f32x4 acc, gacc;
        #pragma unroll
        for (int r = 0; r < 4; r++) { acc[r] = accA[r] + accB[r]; gacc[r] = gacA[r] + gacB[r]; }

        // errS = (v - pred)/1024, already in 16x16x16 A/B operand layout
        s16x4 vv = __builtin_bit_cast(s16x4, vvr[0]);
        s16x4 es, gf;
        #pragma unroll
        for (int r = 0; r < 4; r++) {
            es[r] = (short)f2bf_fast((bf2f((uint16_t)vv[r]) - acc[r]) * (1.0f / 1024.0f));
            gf[r] = (short)f2bf_fast(gacc[r]);
        }

        // out = pred + G @ errS
        f32x4 o = mfma16(gf, es, acc);

        // W update: W += k^T @ errS
        #pragma unroll
        for (int mt = 0; mt < 8; mt++) {
            s16x4 kf = __builtin_bit_cast(s16x4, ktr[mt]);
            W[mt] = mfma16(kf, es, W[mt]);
        }

        // store out chunk (fire-and-forget)
        #pragma unroll
        for (int r = 0; r < 4; r++)
            obase[(size_t)(s0 + 4 * q + r) * 2048 + l15] = f2bf_fast(o[r]);

        // rewrite shadow (same-wave in-order DS: no waitcnt/barrier needed)
        #pragma unroll
        for (int mt = 0; mt < 8; mt++) {
            uint32_t p0 = (uint32_t)f2bf_fast(W[mt][0]) | ((uint32_t)f2bf_fast(W[mt][1]) << 16);
            uint32_t p1 = (uint32_t)f2bf_fast(W[mt][2]) | ((uint32_t)f2bf_fast(W[mt][3]) << 16);
            u32x2 pp; pp[0] = p0; pp[1] = p1;
            *(u32x2*)(wbp + l15 * 136 + 16 * mt + 4 * q) = pp;
        }
    };

    u32x4 afA[4], afB[4];
    u32x2 ktA[8], ktB[8];
    u32x2 vvA[1], vvB[1];
    loadset(0, afA, ktA, vvA);
    loadset(1, afB, ktB, vvB);

    for (int c = 0; c < 128; c += 2) {
        step(c, afA, ktA, vvA);
        if (c < 126) loadset(c + 2, afA, ktA, vvA);
        step(c + 1, afB, ktB, vvB);
        if (c < 126) loadset(c + 3, afB, ktB, vvB);
    }
}

// ---------------------------------------------------------------------------
// LayerNorm over rows of 2048 (biased var), * g + b; X bf16, g/b fp32, Y bf16
// ---------------------------------------------------------------------------
__global__ __launch_bounds__(256) void ln_kernel(
    const uint16_t* __restrict__ X, const float* __restrict__ Gm,
    const float* __restrict__ Bt, uint16_t* __restrict__ Y)
{
    const int row = blockIdx.x, t = threadIdx.x;
    const uint16_t* xr = X + (size_t)row * 2048 + t * 8;
    u32x4 raw = *(const u32x4*)xr;
    const uint16_t* pr = (const uint16_t*)&raw;
    float v[8];
    float s = 0.f, s2 = 0.f;
    for (int i = 0; i < 8; i++) {
        v[i] = bf2f(pr[i]);
        s += v[i];
        s2 += v[i] * v[i];
    }
    for (int off = 32; off; off >>= 1) {
        s  += __shfl_down(s, off, 64);
        s2 += __shfl_down(s2, off, 64);
    }
    __shared__ float red[8];
    if ((t & 63) == 0) { red[(t >> 6) * 2] = s; red[(t >> 6) * 2 + 1] = s2; }
    __syncthreads();
    float ts  = red[0] + red[2] + red[4] + red[6];
    float ts2 = red[1] + red[3] + red[5] + red[7];
    float mu  = ts * (1.0f / 2048.0f);
    float var = ts2 * (1.0f / 2048.0f) - mu * mu;
    float inv = rsqrtf(var + 1e-5f);
    uint16_t outv[8];
    for (int i = 0; i < 8; i++) {
        float y = (v[i] - mu) * inv * Gm[t * 8 + i] + Bt[t * 8 + i];
        outv[i] = f2bf(y);
    }
    u32x4 ov;
    __builtin_memcpy(&ov, outv, 16);
    *(u32x4*)(Y + (size_t)row * 2048 + t * 8) = ov;
}

// ---------------------------------------------------------------------------
extern "C" void kernel_launch(void* const* d_in, const int* in_sizes, int n_in,
                              void* d_out, int out_size, void* d_ws, size_t ws_size,
                              hipStream_t stream)
{
    const float* x  = (const float*)d_in[0];
    const float* Wk = (const float*)d_in[1];
    const float* Wv = (const float*)d_in[2];
    const float* Wo = (const float*)d_in[3];
    const float* lg = (const float*)d_in[4];
    const float* lb = (const float*)d_in[5];
    const float* W0 = (const float*)d_in[6];
    float* out = (float*)d_out;

    const size_t NTOK = 8192, HID = 2048;
    // ws (bf16 elems): xb(->kp after GEMMs) | wbuf | kb | vb | kt | vt  ~176 MB
    uint16_t* xb   = (uint16_t*)d_ws;          // 8192*2048; reused as kp
    uint16_t* wbuf = xb + NTOK * HID;          // 2048*2048
    uint16_t* kb   = wbuf + HID * HID;         // 8192*2048
    uint16_t* vb   = kb + NTOK * HID;          // 8192*2048
    uint16_t* kt   = vb + NTOK * HID;          // 8192*2048
    uint16_t* vt   = kt + NTOK * HID;          // 8192*2048
    uint16_t* kp   = xb;                       // xb dead after both proj GEMMs
    uint16_t* ob   = (uint16_t*)d_out;         // scan out parks in d_out bytes
    uint16_t* lnb  = kb;                       // kb dead after repack

    dim3 grid(8, 32), blk(512);
    const int nX4 = (int)(NTOK * HID / 4), nW4 = (int)(HID * HID / 4);

    cvt_bf16<<<4096, 256, 0, stream>>>(x, xb, nX4);
    cvt_bf16<<<4096, 256, 0, stream>>>(Wk, wbuf, nW4);
    gemm256<false><<<grid, blk, 0, stream>>>(xb, wbuf, kb, nullptr, 8192, 2048, 2048);
    cvt_bf16<<<4096, 256, 0, stream>>>(Wv, wbuf, nW4);
    gemm256<false><<<grid, blk, 0, stream>>>(xb, wbuf, vb, nullptr, 8192, 2048, 2048);
    repack<<<8192, 64, 0, stream>>>(kb, vb, kp, kt, vt);
    ttt_scan<<<512, 64, 0, stream>>>(kp, kt, vt, W0, ob);
    ln_kernel<<<8192, 256, 0, stream>>>(ob, lg, lb, lnb);
    cvt_bf16<<<4096, 256, 0, stream>>>(Wo, wbuf, nW4);
    gemm256<true><<<grid, blk, 0, stream>>>(lnb, wbuf, out, x, 8192, 2048, 2048);
}